// Round 7
// baseline (647.657 us; speedup 1.0000x reference)
//
#include <hip/hip_runtime.h>

// Problem constants
#define BB   8
#define CIN  256
#define COUT 256
#define HH   64
#define WW   64
#define HW   (HH*WW)        // 4096
#define KT   9
#define KTOT (CIN*KT)       // 2304
#define WR   12             // staged (real) window rows
#define RSTR 65             // dwords per window row (odd -> bank mixing)
#define CSTR 911            // dwords per ch slot: 14 rows x 65 + 1 pad

typedef short short8 __attribute__((ext_vector_type(8)));
typedef float f32x4  __attribute__((ext_vector_type(4)));
typedef float f32x2  __attribute__((ext_vector_type(2)));
typedef float f32x16 __attribute__((ext_vector_type(16)));
union FragU { short8 s8; unsigned u[4]; uint4 u4; };

// Workspace layout (float offsets)
#define WS_OFF     0            // [B][2][HW]
#define WS_SCALE   65536        // [B][HW]
#define WS_PART    98304        // 64 partial absmax of w_dcn
#define WS_SDCN    98368        // s_dcn (+3 pad)
#define WS_WOFFQ   98372        // [2][CIN][9]
#define WS_WSCALEQ 102980       // [CIN][9]
#define WS_B       105284       // fp8-int bytes [160][8][64][8] = 655360 B

#define USE_FP8_HW __has_builtin(__builtin_amdgcn_cvt_pk_f32_fp8)

__device__ __forceinline__ float fq(float w, float s) {
    float q = rintf(w / s);              // RNE, matches jnp.round
    q = fminf(fmaxf(q, -8.f), 7.f);
    return q * s;
}

__device__ __forceinline__ unsigned short f2bf(float f) {
    unsigned u = __float_as_uint(f);
    return (unsigned short)((u + 0x7fffu + ((u >> 16) & 1u)) >> 16);  // RNE
}

// 3-op bf16 pair pack (round-half-up, 0.5-ulp bound): low16=bf16(a), hi=bf16(b)
__device__ __forceinline__ unsigned pkbf(float a, float b) {
    unsigned ua = __float_as_uint(a) + 0x8000u;
    unsigned ub = __float_as_uint(b) + 0x8000u;
    return __builtin_amdgcn_perm(ub, ua, 0x07060302u);
}

// =============== K1: absmax partials + small-tensor quant =====================
__global__ __launch_bounds__(256) void prep_kernel(const float* __restrict__ w_dcn,
                                                   const float* __restrict__ w_off,
                                                   const float* __restrict__ w_scale,
                                                   float* __restrict__ ws) {
    __shared__ float red[256];
    const int bx = blockIdx.x, tid = threadIdx.x;
    if (bx < 64) {                       // partial absmax of w_dcn
        float m = 0.f;
        const float* p = w_dcn + bx * 9216;
#pragma unroll
        for (int k = 0; k < 36; ++k) m = fmaxf(m, fabsf(p[tid + k * 256]));
        red[tid] = m;
        __syncthreads();
        for (int s = 128; s > 0; s >>= 1) {
            if (tid < s) red[tid] = fmaxf(red[tid], red[tid + s]);
            __syncthreads();
        }
        if (tid == 0) ws[WS_PART + bx] = red[0];
    } else {                             // small tensors: absmax + quantize
        const float* src = (bx == 64) ? w_off : w_scale;
        const int n = (bx == 64) ? 2 * KTOT : KTOT;
        float* dst = ws + ((bx == 64) ? WS_WOFFQ : WS_WSCALEQ);
        float m = 0.f;
        for (int i = tid; i < n; i += 256) m = fmaxf(m, fabsf(src[i]));
        red[tid] = m;
        __syncthreads();
        for (int s = 128; s > 0; s >>= 1) {
            if (tid < s) red[tid] = fmaxf(red[tid], red[tid + s]);
            __syncthreads();
        }
        float sq = fmaxf(red[0], 1e-8f) / 7.f;
        for (int i = tid; i < n; i += 256) dst[i] = fq(src[i], sq);
    }
}

// =============== K2: offset/scale conv + w_dcn quant to fp8-int B =============
// B byte t = ((s*8 + nt)*64 + l)*8 + j ; s = g*5 + ks (g<32 ch-groups of 8);
// k16 = (l>>5)*8 + j; ch = g*8 + (k16>>1); tap = ks*2 + (k16&1) (9 -> pad 0);
// o = nt*32 + (l&31).
__global__ __launch_bounds__(256) void mid_kernel(const float* __restrict__ x,
                                                  const float* __restrict__ w_dcn,
                                                  float* __restrict__ ws) {
    __shared__ float R[4][3][64];
    __shared__ float Wt[256 * 73];      // [o][u] u = ck within group (72) + pad
    const int bx = blockIdx.x, tid = threadIdx.x;
    if (bx < 512) {
        // ---- offset/scale 3x3 conv, one (b,i) row per block ----
        const int b = bx & 7, i = bx >> 3;
        const int j = tid & 63, cq = tid >> 6;
        const float* woq = ws + WS_WOFFQ;
        const float* wsq = ws + WS_WSCALEQ;
        float a0 = 0.f, a1 = 0.f, a2 = 0.f;
        for (int c = cq * 64; c < cq * 64 + 64; ++c) {
            const float* xb = x + (size_t)(b * CIN + c) * HW;
            const float* w0 = woq + c * 9;
            const float* w1 = woq + KTOT + c * 9;
            const float* w2 = wsq + c * 9;
#pragma unroll
            for (int di = -1; di <= 1; ++di) {
                int yy = i + di;
                bool rv = (yy >= 0) && (yy < HH);
#pragma unroll
                for (int dj = -1; dj <= 1; ++dj) {
                    int xx = j + dj;
                    float xv = (rv && xx >= 0 && xx < WW) ? xb[yy * WW + xx] : 0.f;
                    int t = (di + 1) * 3 + (dj + 1);
                    a0 += xv * w0[t];
                    a1 += xv * w1[t];
                    a2 += xv * w2[t];
                }
            }
        }
        R[cq][0][j] = a0; R[cq][1][j] = a1; R[cq][2][j] = a2;
        __syncthreads();
        if (tid < 192) {
            int comp = tid >> 6, j2 = tid & 63;
            float v = R[0][comp][j2] + R[1][comp][j2] +
                      R[2][comp][j2] + R[3][comp][j2];
            if (comp == 0)      ws[WS_OFF + (b * 2 + 0) * HW + i * WW + j2] = v;
            else if (comp == 1) ws[WS_OFF + (b * 2 + 1) * HW + i * WW + j2] = v;
            else                ws[WS_SCALE + b * HW + i * WW + j2] = v;
        }
    } else {
        // ---- quantize w_dcn -> fp8-int B for channel group g ----
        const int g = bx - 512;           // 0..31
        float m = 0.f;
#pragma unroll
        for (int k = 0; k < 64; ++k) m = fmaxf(m, ws[WS_PART + k]);
        float sd = fmaxf(m, 1e-8f) / 7.f;
        if (g == 0 && tid == 0) ws[WS_SDCN] = sd;
        // stage 256 o x 72 ck (coalesced 72-float rows)
        for (int f = tid; f < 256 * 72; f += 256) {
            int o = f / 72, u = f - o * 72;
            Wt[o * 73 + u] = w_dcn[o * KTOT + g * 72 + u];
        }
        __syncthreads();
#pragma unroll 4
        for (int rep = 0; rep < 20; ++rep) {
            int fd = rep * 256 + tid;     // 0..5119
            int j4 = fd & 1;
            int l  = (fd >> 1) & 63;
            int nt = (fd >> 7) & 7;
            int ks = fd >> 10;            // 0..4
            int s = g * 5 + ks;
            int o = nt * 32 + (l & 31);
            float qv[4];
#pragma unroll
            for (int jj = 0; jj < 4; ++jj) {
                int j = j4 * 4 + jj;
                int k16 = ((l >> 5) << 3) + j;
                int tap = ks * 2 + (k16 & 1);
                float wv = (tap <= 8) ? Wt[o * 73 + (k16 >> 1) * 9 + tap] : 0.f;
                qv[jj] = fminf(fmaxf(rintf(wv / sd), -8.f), 7.f);
            }
            unsigned d;
#if USE_FP8_HW
            d = 0;
            d = __builtin_amdgcn_cvt_pk_fp8_f32(qv[0], qv[1], d, false);
            d = __builtin_amdgcn_cvt_pk_fp8_f32(qv[2], qv[3], d, true);
#else
            d = ((unsigned)(unsigned char)(signed char)(int)qv[0])
              | ((unsigned)(unsigned char)(signed char)(int)qv[1] << 8)
              | ((unsigned)(unsigned char)(signed char)(int)qv[2] << 16)
              | ((unsigned)(unsigned char)(signed char)(int)qv[3] << 24);
#endif
            ((unsigned*)(ws + WS_B))[((s * 8 + nt) * 64 + l) * 2 + j4] = d;
        }
    }
}

// fp8-int x4 -> two packed-bf16 dwords (exact for small ints)
__device__ __forceinline__ void cvt4(unsigned d, unsigned& p0, unsigned& p1) {
#if USE_FP8_HW
    f32x2 lo = __builtin_amdgcn_cvt_pk_f32_fp8(d, false);
    f32x2 hi = __builtin_amdgcn_cvt_pk_f32_fp8(d, true);
    p0 = __builtin_amdgcn_perm(__float_as_uint(lo.y), __float_as_uint(lo.x),
                               0x07060302u);
    p1 = __builtin_amdgcn_perm(__float_as_uint(hi.y), __float_as_uint(hi.x),
                               0x07060302u);
#else
    float f0 = (float)(int)(signed char)(d & 0xff);
    float f1 = (float)(int)(signed char)((d >> 8) & 0xff);
    float f2 = (float)(int)(signed char)((d >> 16) & 0xff);
    float f3 = (float)(int)(signed char)(d >> 24);
    p0 = __builtin_amdgcn_perm(__float_as_uint(f1), __float_as_uint(f0),
                               0x07060302u);
    p1 = __builtin_amdgcn_perm(__float_as_uint(f3), __float_as_uint(f2),
                               0x07060302u);
#endif
}

// =============== K3: main fused deformable conv (MFMA bf16 32x32x16) ==========
// Grid 512, block (b,i): M=64 (2 m-tiles) x N=256 (8 n-tiles), 512 thr/8 waves,
// 3 blocks/CU. K = 32 slabs of 8ch x 5 K-steps (taps paired, tap9 = pad).
// Window: 8 ch x 14 rows (rows 0/13 zeroed spares) of paired-bf16 dwords,
// row stride 65 dw -> one ds_read2_b32 (offsets 0,65) per bilinear sample.
// Produce: balanced 5 quarter-frags/thread -> sA; consume: wave (mtc,ntp)
// reads sA b128 + 2 fp8 B-frags, 2 MFMA/step. Fallback: global gathers.
__global__ __launch_bounds__(512, 6) void dcn_main_kernel(
    const float* __restrict__ x, const float* __restrict__ b_off,
    const float* __restrict__ b_scale, const float* __restrict__ b_dcn,
    const float* __restrict__ ws, float* __restrict__ out) {
    __shared__ unsigned sWin[8 * CSTR];         // 29152 B
    __shared__ short8 sA[5][2][64];             // 10240 B
    __shared__ int sRed[2];
    const int tid = threadIdx.x;
    const int bx = blockIdx.x;
    const int b = bx & 7;                  // XCD swizzle: batch -> XCD
    const int i = bx >> 3;
    const int w = tid >> 6, l = tid & 63;
    const int h = l >> 5, ln31 = l & 31;
    const int mtc = w & 1, ntp = w >> 1;
    const int colp = mtc * 32 + ln31;      // this lane's pixel column
    const float* xb = x + (size_t)b * CIN * HW;
    const char* Bb = (const char*)(ws + WS_B);
    const float sdcn = ws[WS_SDCN];

    if (tid == 0) { sRed[0] = 64; sRed[1] = -1; }

    // ---- phase 0: per-lane bilinear meta for 9 taps (registers) ----
    unsigned mRC[9], mW0[9], mW1[9];
    {
        float o0 = ws[WS_OFF + (b * 2 + 0) * HW + i * WW + colp] + b_off[0];
        float o1 = ws[WS_OFF + (b * 2 + 1) * HW + i * WW + colp] + b_off[1];
        float sc = fmaxf(ws[WS_SCALE + b * HW + i * WW + colp] + b_scale[0], 0.f);
        int rmn = 64, rmx = -1;
#pragma unroll
        for (int tap = 0; tap < 9; ++tap) {
            float ry = (float)(tap / 3 - 1), rx = (float)(tap % 3 - 1);
            float py = (float)i + ry * sc + o0;
            float px = (float)colp + rx * sc + o1;
            float y0f = floorf(py), x0f = floorf(px);
            float wy = py - y0f, wx = px - x0f;
            float w00 = (1.f - wy) * (1.f - wx), w01 = (1.f - wy) * wx;
            float w10 = wy * (1.f - wx),         w11 = wy * wx;
            bool vy0 = (y0f >= 0.f)  && (y0f <= 63.f);
            bool vy1 = (y0f >= -1.f) && (y0f <= 62.f);
            bool vx0 = (x0f >= 0.f)  && (x0f <= 63.f);
            bool vx1 = (x0f >= -1.f) && (x0f <= 62.f);
            bool d0hi = x0f > 62.f, d1lo = x0f < 0.f;
            float e0 = 0.f, e1 = 0.f, e2 = 0.f, e3 = 0.f;
            if (vy0 && vx0) { if (d0hi) e1 += w00; else e0 += w00; }
            if (vy0 && vx1) { if (d1lo) e0 += w01; else e1 += w01; }
            if (vy1 && vx0) { if (d0hi) e3 += w10; else e2 += w10; }
            if (vy1 && vx1) { if (d1lo) e2 += w11; else e3 += w11; }
            int r0 = (int)fminf(fmaxf(y0f, 0.f), 63.f);
            int r1 = (int)fminf(fmaxf(y0f + 1.f, 0.f), 63.f);
            int cb = (int)fminf(fmaxf(x0f, 0.f), 62.f);
            bool use0 = (e0 != 0.f) || (e1 != 0.f);
            bool use1 = (e2 != 0.f) || (e3 != 0.f);
            if (use0) { rmn = min(rmn, r0); rmx = max(rmx, r0); }
            if (use1) { rmn = min(rmn, r1); rmx = max(rmx, r1); }
            mRC[tap] = (unsigned)r0 | ((unsigned)r1 << 8) | ((unsigned)cb << 16) |
                       ((unsigned)use0 << 24) | ((unsigned)use1 << 25);
            mW0[tap] = (unsigned)f2bf(e0 * sdcn) | ((unsigned)f2bf(e1 * sdcn) << 16);
            mW1[tap] = (unsigned)f2bf(e2 * sdcn) | ((unsigned)f2bf(e3 * sdcn) << 16);
        }
        __syncthreads();                  // sRed init visible
        atomicMin(&sRed[0], rmn);
        atomicMax(&sRed[1], rmx);
    }
    __syncthreads();
    const int rmin = sRed[0], rmax = sRed[1];
    const int rlo = min(max(rmin, 0), HH - WR);
    const bool fast = (rmax - rlo) <= (WR - 1);

    // fast-mode dword offset (within ch slot) of the TOP row of each stencil;
    // bottom row is always at +65 dw (read2 offset1). Weight-0 rows remap to
    // valid/zeroed rows.
    int aoff[9];
#pragma unroll
    for (int tap = 0; tap < 9; ++tap) {
        unsigned rc = mRC[tap];
        int r0 = rc & 0xff, r1 = (rc >> 8) & 0xff, cb = (rc >> 16) & 0xff;
        int u0 = (rc >> 24) & 1, u1 = (rc >> 25) & 1;
        int ridx = u0 ? (r0 - rlo + 1) : (u1 ? (r1 - rlo) : 0);
        aoff[tap] = ridx * RSTR + cb;
    }

    f32x16 acc0, acc1;
#pragma unroll
    for (int r = 0; r < 16; ++r) { acc0[r] = 0.f; acc1[r] = 0.f; }

    // ---- produce: 5 quarter-frags per thread (balanced) ----
    auto produceFast = [&](int g) {
        (void)g;
#pragma unroll
        for (int u = 0; u < 5; ++u) {
            int qf = ntp * 5 + u;
            int ksl = qf >> 2, jc = qf & 3;
            int chl = h * 4 + jc;
            const unsigned* slot = sWin + chl * CSTR;
            // tap0 = 2*ksl (always <=8)
            const unsigned* p = slot + aoff[2 * ksl];
            unsigned dw0 = p[0], dw1 = p[RSTR];
            float w00 = __uint_as_float(mW0[2 * ksl] << 16);
            float w01 = __uint_as_float(mW0[2 * ksl] & 0xffff0000u);
            float w10 = __uint_as_float(mW1[2 * ksl] << 16);
            float w11 = __uint_as_float(mW1[2 * ksl] & 0xffff0000u);
            float v0 = w00 * __uint_as_float(dw0 << 16) +
                       w01 * __uint_as_float(dw0 & 0xffff0000u) +
                       w10 * __uint_as_float(dw1 << 16) +
                       w11 * __uint_as_float(dw1 & 0xffff0000u);
            float v1 = 0.f;
            if (ksl < 4) {                // tap1 = 2*ksl+1 <= 7
                const unsigned* q = slot + aoff[2 * ksl + 1];
                unsigned dq0 = q[0], dq1 = q[RSTR];
                float z00 = __uint_as_float(mW0[2 * ksl + 1] << 16);
                float z01 = __uint_as_float(mW0[2 * ksl + 1] & 0xffff0000u);
                float z10 = __uint_as_float(mW1[2 * ksl + 1] << 16);
                float z11 = __uint_as_float(mW1[2 * ksl + 1] & 0xffff0000u);
                v1 = z00 * __uint_as_float(dq0 << 16) +
                     z01 * __uint_as_float(dq0 & 0xffff0000u) +
                     z10 * __uint_as_float(dq1 << 16) +
                     z11 * __uint_as_float(dq1 & 0xffff0000u);
            }
            ((unsigned*)&sA[ksl][mtc][l])[jc] = pkbf(v0, v1);
        }
    };
    auto produceSlow = [&](int g) {
#pragma unroll
        for (int u = 0; u < 5; ++u) {
            int qf = ntp * 5 + u;
            int ksl = qf >> 2, jc = qf & 3;
            int chl = h * 4 + jc;
            const float* pl = xb + (size_t)(g * 8 + chl) * HW;
            float vv[2];
#pragma unroll
            for (int t = 0; t < 2; ++t) {
                int tap = 2 * ksl + t;
                if (tap > 8) { vv[t] = 0.f; continue; }
                unsigned rc = mRC[tap];
                int r0 = rc & 0xff, r1 = (rc >> 8) & 0xff, cb = (rc >> 16) & 0xff;
                float w00 = __uint_as_float(mW0[tap] << 16);
                float w01 = __uint_as_float(mW0[tap] & 0xffff0000u);
                float w10 = __uint_as_float(mW1[tap] << 16);
                float w11 = __uint_as_float(mW1[tap] & 0xffff0000u);
                const float* p0 = pl + r0 * WW + cb;
                const float* p1 = pl + r1 * WW + cb;
                vv[t] = w00 * p0[0] + w01 * p0[1] + w10 * p1[0] + w11 * p1[1];
            }
            ((unsigned*)&sA[ksl][mtc][l])[jc] = pkbf(vv[0], vv[1]);
        }
    };

    // ---- consume 5 K-steps of slab g ----
    auto consume = [&](int g) {
        const char* bp = Bb + ((size_t)(g * 5 * 8 + ntp * 2) * 64 + l) * 8;
#pragma unroll
        for (int ks = 0; ks < 5; ++ks) {
            uint2 ra = *(const uint2*)(bp + ks * 4096);
            uint2 rb = *(const uint2*)(bp + ks * 4096 + 512);
            FragU b0, b1;
            cvt4(ra.x, b0.u[0], b0.u[1]); cvt4(ra.y, b0.u[2], b0.u[3]);
            cvt4(rb.x, b1.u[0], b1.u[1]); cvt4(rb.y, b1.u[2], b1.u[3]);
            short8 af = sA[ks][mtc][l];
            acc0 = __builtin_amdgcn_mfma_f32_32x32x16_bf16(af, b0.s8, acc0, 0, 0, 0);
            acc1 = __builtin_amdgcn_mfma_f32_32x32x16_bf16(af, b1.s8, acc1, 0, 0, 0);
        }
    };

    // ---- window staging: wave w = channel w; 3 chunks of 4 rows ----
    auto stage = [&](int g) {
        const int seg = l & 15;
#pragma unroll
        for (int c = 0; c < 3; ++c) {
            int row = (l >> 4) + c * 4;   // 0..11
            const float* src = xb + (size_t)(g * 8 + w) * HW +
                               (rlo + row) * WW + seg * 4;
            float4 a = *(const float4*)src;
            float b5 = (seg == 15) ? a.w : src[4];
            unsigned* wp = &sWin[w * CSTR + (row + 1) * RSTR + seg * 4];
            wp[0] = pkbf(a.x, a.y);
            wp[1] = pkbf(a.y, a.z);
            wp[2] = pkbf(a.z, a.w);
            wp[3] = pkbf(a.w, b5);
        }
    };

    if (fast) {
        // zero spare rows 0 and 13 of each ch slot (garbage must not be NaN)
        for (int e = tid; e < 8 * 130; e += 512) {
            int c = e / 130, r = e - c * 130;
            sWin[c * CSTR + (r < 65 ? r : 13 * RSTR + (r - 65))] = 0u;
        }
        stage(0);
        __syncthreads();
        produceFast(0);
        __syncthreads();
        for (int g = 0; g < 32; ++g) {
            consume(g);
            if (g < 31) stage(g + 1);
            __syncthreads();
            if (g < 31) produceFast(g + 1);
            __syncthreads();
        }
    } else {
        for (int g = 0; g < 32; ++g) {
            produceSlow(g);
            __syncthreads();
            consume(g);
            __syncthreads();
        }
    }

    // ---- epilogue (32x32 C layout: col=lane&31=o-col, row=(reg&3)+8*(reg>>2)+4h)
#pragma unroll
    for (int t = 0; t < 2; ++t) {
        f32x16 A = t ? acc1 : acc0;
        int o = (ntp * 2 + t) * 32 + ln31;
        float bb = b_dcn[o];
        float* ob = out + ((size_t)(b * COUT + o) * HH + i) * WW + mtc * 32 + 4 * h;
#pragma unroll
        for (int rq = 0; rq < 4; ++rq) {
            f32x4 v = {A[rq * 4 + 0] + bb, A[rq * 4 + 1] + bb,
                       A[rq * 4 + 2] + bb, A[rq * 4 + 3] + bb};
            *(f32x4*)(ob + rq * 8) = v;
        }
    }
}

extern "C" void kernel_launch(void* const* d_in, const int* in_sizes, int n_in,
                              void* d_out, int out_size, void* d_ws, size_t ws_size,
                              hipStream_t stream) {
    const float* x       = (const float*)d_in[0];
    const float* w_off   = (const float*)d_in[1];
    const float* b_off   = (const float*)d_in[2];
    const float* w_scale = (const float*)d_in[3];
    const float* b_scale = (const float*)d_in[4];
    const float* w_dcn   = (const float*)d_in[5];
    const float* b_dcn   = (const float*)d_in[6];
    float* out = (float*)d_out;
    float* ws  = (float*)d_ws;

    prep_kernel<<<dim3(66),  dim3(256), 0, stream>>>(w_dcn, w_off, w_scale, ws);
    mid_kernel <<<dim3(544), dim3(256), 0, stream>>>(x, w_dcn, ws);
    dcn_main_kernel<<<dim3(512), dim3(512), 0, stream>>>(
        x, b_off, b_scale, b_dcn, ws, out);
}

// Round 8
// 250.875 us; speedup vs baseline: 2.5816x; 2.5816x over previous
//
#include <hip/hip_runtime.h>

// Problem constants
#define BB   8
#define CIN  256
#define COUT 256
#define HH   64
#define WW   64
#define HW   (HH*WW)        // 4096
#define KT   9
#define KTOT (CIN*KT)       // 2304
#define WR   12             // max staged (real) window rows
#define RSTR 65             // dwords per window row (odd -> bank mixing)
#define CSTR 911            // dwords per ch slot: 14 rows x 65 + 1 pad

typedef short short8 __attribute__((ext_vector_type(8)));
typedef float f32x4  __attribute__((ext_vector_type(4)));
typedef float f32x2  __attribute__((ext_vector_type(2)));
typedef float f32x16 __attribute__((ext_vector_type(16)));
union FragU { short8 s8; unsigned u[4]; uint4 u4; };

// Workspace layout (float offsets)
#define WS_OFF     0            // [B][2][HW]
#define WS_SCALE   65536        // [B][HW]
#define WS_PART    98304        // 64 partial absmax of w_dcn
#define WS_SDCN    98368        // s_dcn (+3 pad)
#define WS_WOFFQ   98372        // [2][CIN][9]
#define WS_WSCALEQ 102980       // [CIN][9]
#define WS_B       105284       // fp8-int bytes [160][8][64][8] = 655360 B

#define USE_FP8_HW __has_builtin(__builtin_amdgcn_cvt_pk_f32_fp8)
#define HI16 0xffff0000u

__device__ __forceinline__ float fq(float w, float s) {
    float q = rintf(w / s);              // RNE, matches jnp.round
    q = fminf(fmaxf(q, -8.f), 7.f);
    return q * s;
}

__device__ __forceinline__ unsigned short f2bf(float f) {
    unsigned u = __float_as_uint(f);
    return (unsigned short)((u + 0x7fffu + ((u >> 16) & 1u)) >> 16);  // RNE
}

// 3-op bf16 pair pack (round-half-up, 0.5-ulp bound): low16=bf16(a), hi=bf16(b)
__device__ __forceinline__ unsigned pkbf(float a, float b) {
    unsigned ua = __float_as_uint(a) + 0x8000u;
    unsigned ub = __float_as_uint(b) + 0x8000u;
    return __builtin_amdgcn_perm(ub, ua, 0x07060302u);
}

// =============== K1: absmax partials + small-tensor quant =====================
__global__ __launch_bounds__(256) void prep_kernel(const float* __restrict__ w_dcn,
                                                   const float* __restrict__ w_off,
                                                   const float* __restrict__ w_scale,
                                                   float* __restrict__ ws) {
    __shared__ float red[256];
    const int bx = blockIdx.x, tid = threadIdx.x;
    if (bx < 64) {                       // partial absmax of w_dcn
        float m = 0.f;
        const float* p = w_dcn + bx * 9216;
#pragma unroll
        for (int k = 0; k < 36; ++k) m = fmaxf(m, fabsf(p[tid + k * 256]));
        red[tid] = m;
        __syncthreads();
        for (int s = 128; s > 0; s >>= 1) {
            if (tid < s) red[tid] = fmaxf(red[tid], red[tid + s]);
            __syncthreads();
        }
        if (tid == 0) ws[WS_PART + bx] = red[0];
    } else {                             // small tensors: absmax + quantize
        const float* src = (bx == 64) ? w_off : w_scale;
        const int n = (bx == 64) ? 2 * KTOT : KTOT;
        float* dst = ws + ((bx == 64) ? WS_WOFFQ : WS_WSCALEQ);
        float m = 0.f;
        for (int i = tid; i < n; i += 256) m = fmaxf(m, fabsf(src[i]));
        red[tid] = m;
        __syncthreads();
        for (int s = 128; s > 0; s >>= 1) {
            if (tid < s) red[tid] = fmaxf(red[tid], red[tid + s]);
            __syncthreads();
        }
        float sq = fmaxf(red[0], 1e-8f) / 7.f;
        for (int i = tid; i < n; i += 256) dst[i] = fq(src[i], sq);
    }
}

// =============== K2a: offset/scale 3x3 conv (strip x ch-chunk, atomicAdd) =====
__global__ __launch_bounds__(512) void convos_kernel(const float* __restrict__ x,
                                                     float* __restrict__ ws) {
    const int bx = blockIdx.x, tid = threadIdx.x;
    const int b = bx & 7, strip = (bx >> 3) & 7, chunk = bx >> 6;   // 8 x 8 x 8
    const int r = strip * 8 + (tid >> 6), j = tid & 63;
    const float* woq = ws + WS_WOFFQ;
    const float* wsq = ws + WS_WSCALEQ;
    // 9 clamped offsets + validity masks (tap-constant across channels)
    int offc[9]; float vm[9];
#pragma unroll
    for (int di = -1; di <= 1; ++di)
#pragma unroll
        for (int dj = -1; dj <= 1; ++dj) {
            int t = (di + 1) * 3 + (dj + 1);
            int yy = r + di, xx = j + dj;
            bool v = (yy >= 0) && (yy < HH) && (xx >= 0) && (xx < WW);
            offc[t] = min(max(yy, 0), HH - 1) * WW + min(max(xx, 0), WW - 1);
            vm[t] = v ? 1.f : 0.f;
        }
    float a0 = 0.f, a1 = 0.f, a2 = 0.f;
    for (int c = chunk * 32; c < chunk * 32 + 32; ++c) {
        const float* pl = x + (size_t)(b * CIN + c) * HW;
        const float* w0 = woq + c * 9;
        const float* w1 = woq + KTOT + c * 9;
        const float* w2 = wsq + c * 9;
#pragma unroll
        for (int t = 0; t < 9; ++t) {
            float xv = pl[offc[t]] * vm[t];
            a0 += xv * w0[t];
            a1 += xv * w1[t];
            a2 += xv * w2[t];
        }
    }
    atomicAdd(ws + WS_OFF + (size_t)(b * 2 + 0) * HW + r * WW + j, a0);
    atomicAdd(ws + WS_OFF + (size_t)(b * 2 + 1) * HW + r * WW + j, a1);
    atomicAdd(ws + WS_SCALE + (size_t)b * HW + r * WW + j, a2);
}

// =============== K2b: w_dcn quant -> fp8-int B fragments ======================
// B byte t = ((s*8 + nt)*64 + l)*8 + j ; s = g*5 + ks (g<32 ch-groups of 8);
// k16 = (l>>5)*8 + j; ch = g*8 + (k16>>1); tap = ks*2 + (k16&1) (9 -> pad 0);
// o = nt*32 + (l&31).
__global__ __launch_bounds__(256) void quantb_kernel(const float* __restrict__ w_dcn,
                                                     float* __restrict__ ws) {
    __shared__ float Wt[256 * 73];      // [o][u] u = ck within group (72) + pad
    const int g = blockIdx.x, tid = threadIdx.x;   // g: 0..31
    float m = 0.f;
#pragma unroll
    for (int k = 0; k < 64; ++k) m = fmaxf(m, ws[WS_PART + k]);
    float sd = fmaxf(m, 1e-8f) / 7.f;
    if (g == 0 && tid == 0) ws[WS_SDCN] = sd;
    // stage 256 o x 72 ck (coalesced 72-float rows)
    for (int f = tid; f < 256 * 72; f += 256) {
        int o = f / 72, u = f - o * 72;
        Wt[o * 73 + u] = w_dcn[o * KTOT + g * 72 + u];
    }
    __syncthreads();
#pragma unroll 4
    for (int rep = 0; rep < 20; ++rep) {
        int fd = rep * 256 + tid;     // 0..5119
        int j4 = fd & 1;
        int l  = (fd >> 1) & 63;
        int nt = (fd >> 7) & 7;
        int ks = fd >> 10;            // 0..4
        int s = g * 5 + ks;
        int o = nt * 32 + (l & 31);
        float qv[4];
#pragma unroll
        for (int jj = 0; jj < 4; ++jj) {
            int j = j4 * 4 + jj;
            int k16 = ((l >> 5) << 3) + j;
            int tap = ks * 2 + (k16 & 1);
            float wv = (tap <= 8) ? Wt[o * 73 + (k16 >> 1) * 9 + tap] : 0.f;
            qv[jj] = fminf(fmaxf(rintf(wv / sd), -8.f), 7.f);
        }
        unsigned d;
#if USE_FP8_HW
        d = 0;
        d = __builtin_amdgcn_cvt_pk_fp8_f32(qv[0], qv[1], d, false);
        d = __builtin_amdgcn_cvt_pk_fp8_f32(qv[2], qv[3], d, true);
#else
        d = ((unsigned)(unsigned char)(signed char)(int)qv[0])
          | ((unsigned)(unsigned char)(signed char)(int)qv[1] << 8)
          | ((unsigned)(unsigned char)(signed char)(int)qv[2] << 16)
          | ((unsigned)(unsigned char)(signed char)(int)qv[3] << 24);
#endif
        ((unsigned*)(ws + WS_B))[((s * 8 + nt) * 64 + l) * 2 + j4] = d;
    }
}

// fp8-int x4 -> two packed-bf16 dwords (exact for small ints)
__device__ __forceinline__ void cvt4(unsigned d, unsigned& p0, unsigned& p1) {
#if USE_FP8_HW
    f32x2 lo = __builtin_amdgcn_cvt_pk_f32_fp8(d, false);
    f32x2 hi = __builtin_amdgcn_cvt_pk_f32_fp8(d, true);
    p0 = __builtin_amdgcn_perm(__float_as_uint(lo.y), __float_as_uint(lo.x),
                               0x07060302u);
    p1 = __builtin_amdgcn_perm(__float_as_uint(hi.y), __float_as_uint(hi.x),
                               0x07060302u);
#else
    float f0 = (float)(int)(signed char)(d & 0xff);
    float f1 = (float)(int)(signed char)((d >> 8) & 0xff);
    float f2 = (float)(int)(signed char)((d >> 16) & 0xff);
    float f3 = (float)(int)(signed char)(d >> 24);
    p0 = __builtin_amdgcn_perm(__float_as_uint(f1), __float_as_uint(f0),
                               0x07060302u);
    p1 = __builtin_amdgcn_perm(__float_as_uint(f3), __float_as_uint(f2),
                               0x07060302u);
#endif
}

// =============== K3: main fused deformable conv (MFMA bf16 32x32x16) ==========
// Grid 512, block (b,i): M=64 (2 m-tiles) x N=256 (8 n-tiles), 512 thr/8 waves.
// K = 32 slabs of 8ch x 5 K-steps (taps paired, tap9 = zero-weight pad).
// Window: 8 ch x adaptive Rn rows (<=12) of paired-bf16 dwords at +1 slot,
// whole window zeroed once; 1 ds_read2_b32 per bilinear sample.
// Produce: FLAT mapping tid -> sA dword u*512+tid (compile-time u only ->
// meta arrays stay in VGPRs; lane-consecutive LDS writes = conflict-free).
// Consume: wave (mtc=w&1, ntp=w>>1): 1 A b128 + 2 fp8 B-frags, 2 MFMA/step.
// Fallback to global gathers if row-span > 12.
__global__ __launch_bounds__(512, 4) void dcn_main_kernel(
    const float* __restrict__ x, const float* __restrict__ b_off,
    const float* __restrict__ b_scale, const float* __restrict__ b_dcn,
    const float* __restrict__ ws, float* __restrict__ out) {
    __shared__ unsigned sWin[8 * CSTR];         // 29152 B
    __shared__ short8 sA[5][2][64];             // 10240 B
    __shared__ int sRed[2];
    const int tid = threadIdx.x;
    const int bx = blockIdx.x;
    const int b = bx & 7;                  // XCD swizzle: batch -> XCD
    const int i = bx >> 3;
    const int w = tid >> 6, l = tid & 63;
    const int h = l >> 5, ln31 = l & 31;
    const int mtc = w & 1, ntp = w >> 1;   // consume roles
    // produce roles (flat): tid = pmt*256 + plp*4 + pjc
    const int pjc = tid & 3, plp = (tid >> 2) & 63, pmt = tid >> 8;
    const int pchl = (plp >> 5) * 4 + pjc;
    const int colp = pmt * 32 + (plp & 31);    // produce/meta pixel column
    const float* xb = x + (size_t)b * CIN * HW;
    const char* Bb = (const char*)(ws + WS_B);
    const float sdcn = ws[WS_SDCN];

    if (tid == 0) { sRed[0] = 64; sRed[1] = -1; }

    // ---- phase 0: per-lane bilinear meta for 9 taps (registers) ----
    unsigned mRCa[9], mW0[9], mW1[9];   // mRCa: packed r0/r1/cb/use, later offsets
    {
        float o0 = ws[WS_OFF + (b * 2 + 0) * HW + i * WW + colp] + b_off[0];
        float o1 = ws[WS_OFF + (b * 2 + 1) * HW + i * WW + colp] + b_off[1];
        float sc = fmaxf(ws[WS_SCALE + b * HW + i * WW + colp] + b_scale[0], 0.f);
        int rmn = 64, rmx = -1;
#pragma unroll
        for (int tap = 0; tap < 9; ++tap) {
            float ry = (float)(tap / 3 - 1), rx = (float)(tap % 3 - 1);
            float py = (float)i + ry * sc + o0;
            float px = (float)colp + rx * sc + o1;
            float y0f = floorf(py), x0f = floorf(px);
            float wy = py - y0f, wx = px - x0f;
            float w00 = (1.f - wy) * (1.f - wx), w01 = (1.f - wy) * wx;
            float w10 = wy * (1.f - wx),         w11 = wy * wx;
            bool vy0 = (y0f >= 0.f)  && (y0f <= 63.f);
            bool vy1 = (y0f >= -1.f) && (y0f <= 62.f);
            bool vx0 = (x0f >= 0.f)  && (x0f <= 63.f);
            bool vx1 = (x0f >= -1.f) && (x0f <= 62.f);
            bool d0hi = x0f > 62.f, d1lo = x0f < 0.f;
            float e0 = 0.f, e1 = 0.f, e2 = 0.f, e3 = 0.f;
            if (vy0 && vx0) { if (d0hi) e1 += w00; else e0 += w00; }
            if (vy0 && vx1) { if (d1lo) e0 += w01; else e1 += w01; }
            if (vy1 && vx0) { if (d0hi) e3 += w10; else e2 += w10; }
            if (vy1 && vx1) { if (d1lo) e2 += w11; else e3 += w11; }
            int r0 = (int)fminf(fmaxf(y0f, 0.f), 63.f);
            int r1 = (int)fminf(fmaxf(y0f + 1.f, 0.f), 63.f);
            int cb = (int)fminf(fmaxf(x0f, 0.f), 62.f);
            bool use0 = (e0 != 0.f) || (e1 != 0.f);
            bool use1 = (e2 != 0.f) || (e3 != 0.f);
            if (use0) { rmn = min(rmn, r0); rmx = max(rmx, r0); }
            if (use1) { rmn = min(rmn, r1); rmx = max(rmx, r1); }
            mRCa[tap] = (unsigned)r0 | ((unsigned)r1 << 8) | ((unsigned)cb << 16) |
                        ((unsigned)use0 << 24) | ((unsigned)use1 << 25);
            mW0[tap] = (unsigned)f2bf(e0 * sdcn) | ((unsigned)f2bf(e1 * sdcn) << 16);
            mW1[tap] = (unsigned)f2bf(e2 * sdcn) | ((unsigned)f2bf(e3 * sdcn) << 16);
        }
        __syncthreads();                  // sRed init visible
        atomicMin(&sRed[0], rmn);
        atomicMax(&sRed[1], rmx);
    }
    __syncthreads();
    int rmin = sRed[0], rmax = sRed[1];
    if (rmax < rmin) { rmin = 0; rmax = 0; }   // degenerate: all weights zero
    const int rlo = rmin;
    const int Rn = rmax - rmin + 1;
    const bool fast = (Rn <= WR);

    // convert meta to mode-specific offsets (compile-time indices only)
#pragma unroll
    for (int tap = 0; tap < 9; ++tap) {
        unsigned rc = mRCa[tap];
        int r0 = rc & 0xff, r1 = (rc >> 8) & 0xff, cb = (rc >> 16) & 0xff;
        int u0 = (rc >> 24) & 1, u1 = (rc >> 25) & 1;
        if (fast) {
            int ridx = u0 ? (r0 - rlo + 1) : (u1 ? (r1 - rlo) : 0);
            mRCa[tap] = (unsigned)(ridx * RSTR + cb);            // dword offset
        } else {
            mRCa[tap] = (unsigned)((r0 * WW + cb) * 4) |
                        ((unsigned)((r1 * WW + cb) * 4) << 16);  // byte offsets
        }
    }

    f32x16 acc0, acc1;
#pragma unroll
    for (int r = 0; r < 16; ++r) { acc0[r] = 0.f; acc1[r] = 0.f; }

    // ---- produce: flat mapping, fully unrolled (compile-time taps) ----
    auto produceFast = [&]() {
        const unsigned* slot = sWin + pchl * CSTR;
#pragma unroll
        for (int u = 0; u < 5; ++u) {
            unsigned o0 = mRCa[2 * u];
            unsigned d00 = slot[o0], d01 = slot[o0 + RSTR];
            float v0 = __uint_as_float(mW0[2 * u] << 16) * __uint_as_float(d00 << 16) +
                       __uint_as_float(mW0[2 * u] & HI16) * __uint_as_float(d00 & HI16) +
                       __uint_as_float(mW1[2 * u] << 16) * __uint_as_float(d01 << 16) +
                       __uint_as_float(mW1[2 * u] & HI16) * __uint_as_float(d01 & HI16);
            float v1 = 0.f;
            if (u < 4) {
                unsigned o1 = mRCa[2 * u + 1];
                unsigned d10 = slot[o1], d11 = slot[o1 + RSTR];
                v1 = __uint_as_float(mW0[2 * u + 1] << 16) * __uint_as_float(d10 << 16) +
                     __uint_as_float(mW0[2 * u + 1] & HI16) * __uint_as_float(d10 & HI16) +
                     __uint_as_float(mW1[2 * u + 1] << 16) * __uint_as_float(d11 << 16) +
                     __uint_as_float(mW1[2 * u + 1] & HI16) * __uint_as_float(d11 & HI16);
            }
            ((unsigned*)sA)[u * 512 + tid] = pkbf(v0, v1);
        }
    };
    auto produceSlow = [&](int g) {
        const char* pl = (const char*)(xb + (size_t)(g * 8 + pchl) * HW);
#pragma unroll
        for (int u = 0; u < 5; ++u) {
            unsigned o0 = mRCa[2 * u];
            const float* p0 = (const float*)(pl + (o0 & 0xffffu));
            const float* p1 = (const float*)(pl + (o0 >> 16));
            float v0 = __uint_as_float(mW0[2 * u] << 16) * p0[0] +
                       __uint_as_float(mW0[2 * u] & HI16) * p0[1] +
                       __uint_as_float(mW1[2 * u] << 16) * p1[0] +
                       __uint_as_float(mW1[2 * u] & HI16) * p1[1];
            float v1 = 0.f;
            if (u < 4) {
                unsigned o1 = mRCa[2 * u + 1];
                const float* q0 = (const float*)(pl + (o1 & 0xffffu));
                const float* q1 = (const float*)(pl + (o1 >> 16));
                v1 = __uint_as_float(mW0[2 * u + 1] << 16) * q0[0] +
                     __uint_as_float(mW0[2 * u + 1] & HI16) * q0[1] +
                     __uint_as_float(mW1[2 * u + 1] << 16) * q1[0] +
                     __uint_as_float(mW1[2 * u + 1] & HI16) * q1[1];
            }
            ((unsigned*)sA)[u * 512 + tid] = pkbf(v0, v1);
        }
    };

    // ---- consume 5 K-steps of slab g ----
    auto consume = [&](int g) {
        const char* bp = Bb + ((size_t)(g * 5 * 8 + ntp * 2) * 64 + l) * 8;
#pragma unroll
        for (int ks = 0; ks < 5; ++ks) {
            uint2 ra = *(const uint2*)(bp + ks * 4096);
            uint2 rb = *(const uint2*)(bp + ks * 4096 + 512);
            FragU b0, b1;
            cvt4(ra.x, b0.u[0], b0.u[1]); cvt4(ra.y, b0.u[2], b0.u[3]);
            cvt4(rb.x, b1.u[0], b1.u[1]); cvt4(rb.y, b1.u[2], b1.u[3]);
            short8 af = sA[ks][mtc][l];
            acc0 = __builtin_amdgcn_mfma_f32_32x32x16_bf16(af, b0.s8, acc0, 0, 0, 0);
            acc1 = __builtin_amdgcn_mfma_f32_32x32x16_bf16(af, b1.s8, acc1, 0, 0, 0);
        }
    };

    // ---- adaptive window staging: wave w = channel w; rows rr < Rn ----
    auto stage = [&](int g) {
        const int seg = l & 15;
        const float* srcb = xb + (size_t)(g * 8 + w) * HW;
        for (int rr = (l >> 4); rr < Rn; rr += 4) {
            const float* src = srcb + (rlo + rr) * WW + seg * 4;
            float4 a = *(const float4*)src;
            float b5 = (seg == 15) ? a.w : src[4];
            unsigned* wp = &sWin[w * CSTR + (rr + 1) * RSTR + seg * 4];
            wp[0] = pkbf(a.x, a.y);
            wp[1] = pkbf(a.y, a.z);
            wp[2] = pkbf(a.z, a.w);
            wp[3] = pkbf(a.w, b5);
        }
    };

    if (fast) {
        for (int e = tid; e < 8 * CSTR; e += 512) sWin[e] = 0u;  // zero once
        __syncthreads();
        stage(0);
        __syncthreads();
        produceFast();
        __syncthreads();
        for (int g = 0; g < 32; ++g) {
            consume(g);
            if (g < 31) stage(g + 1);
            __syncthreads();
            if (g < 31) {
                produceFast();
                __syncthreads();
            }
        }
    } else {
        for (int g = 0; g < 32; ++g) {
            produceSlow(g);
            __syncthreads();
            consume(g);
            __syncthreads();
        }
    }

    // ---- epilogue (32x32 C layout: col=lane&31=o-col, row=(reg&3)+8*(reg>>2)+4h)
#pragma unroll
    for (int t = 0; t < 2; ++t) {
        f32x16 A = t ? acc1 : acc0;
        int o = (ntp * 2 + t) * 32 + ln31;
        float bb = b_dcn[o];
        float* ob = out + ((size_t)(b * COUT + o) * HH + i) * WW + mtc * 32 + 4 * h;
#pragma unroll
        for (int rq = 0; rq < 4; ++rq) {
            f32x4 v = {A[rq * 4 + 0] + bb, A[rq * 4 + 1] + bb,
                       A[rq * 4 + 2] + bb, A[rq * 4 + 3] + bb};
            *(f32x4*)(ob + rq * 8) = v;
        }
    }
}

extern "C" void kernel_launch(void* const* d_in, const int* in_sizes, int n_in,
                              void* d_out, int out_size, void* d_ws, size_t ws_size,
                              hipStream_t stream) {
    const float* x       = (const float*)d_in[0];
    const float* w_off   = (const float*)d_in[1];
    const float* b_off   = (const float*)d_in[2];
    const float* w_scale = (const float*)d_in[3];
    const float* b_scale = (const float*)d_in[4];
    const float* w_dcn   = (const float*)d_in[5];
    const float* b_dcn   = (const float*)d_in[6];
    float* out = (float*)d_out;
    float* ws  = (float*)d_ws;

    // zero the off/scale accumulators (conv uses atomicAdd)
    hipMemsetAsync(d_ws, 0, (size_t)(WS_SCALE + BB * HW) * sizeof(float), stream);

    prep_kernel  <<<dim3(66),  dim3(256), 0, stream>>>(w_dcn, w_off, w_scale, ws);
    convos_kernel<<<dim3(512), dim3(512), 0, stream>>>(x, ws);
    quantb_kernel<<<dim3(32),  dim3(256), 0, stream>>>(w_dcn, ws);
    dcn_main_kernel<<<dim3(512), dim3(512), 0, stream>>>(
        x, b_off, b_scale, b_dcn, ws, out);
}